// Round 1
// baseline (365.408 us; speedup 1.0000x reference)
//
#include <hip/hip_runtime.h>

// Problem: hidden-size-1 LSTM, B=32768 chains, 1024 open-loop + 512 closed-loop steps.
// One thread per batch element; entire recurrence in registers.
// Gate order (PyTorch): i, f, g, o.  b = b_ih + b_hh.
// sigmoid(z) = 1/(1+exp2(-L2E*z)); tanh(z) = 1 - 2/(1+exp2(2*L2E*z)).
// Scale factors folded into per-gate weight constants (uniform -> SGPRs).

#define L2E 1.44269504088896340736f
#define B_TOT 32768
#define T_IN 1024
#define STEPS 512

__device__ __forceinline__ float ex2(float x) { return __builtin_amdgcn_exp2f(x); }
__device__ __forceinline__ float rcp(float x) { return __builtin_amdgcn_rcpf(x); }

struct Consts {
    float Ai, Bi, Ci;   // sigmoid-i (pre-scaled by -L2E)
    float Af, Bf, Cf;   // sigmoid-f
    float Ag, Bg, Cg;   // tanh-g   (pre-scaled by +2*L2E)
    float Ao, Bo, Co;   // sigmoid-o
};

__device__ __forceinline__ void lstm_step(float xv, float& h, float& c, const Consts& K) {
    float zi = fmaf(h, K.Bi, fmaf(xv, K.Ai, K.Ci));
    float zf = fmaf(h, K.Bf, fmaf(xv, K.Af, K.Cf));
    float zg = fmaf(h, K.Bg, fmaf(xv, K.Ag, K.Cg));
    float zo = fmaf(h, K.Bo, fmaf(xv, K.Ao, K.Co));
    float ri = rcp(1.0f + ex2(zi));          // = sigmoid(gate_i)
    float rf = rcp(1.0f + ex2(zf));          // = sigmoid(gate_f)
    float rg = rcp(1.0f + ex2(zg));          // 1/(1+e^{2g})
    float ro = rcp(1.0f + ex2(zo));          // = sigmoid(gate_o)
    float g  = fmaf(-2.0f, rg, 1.0f);        // tanh(gate_g)
    c = fmaf(rf, c, ri * g);
    float rc = rcp(1.0f + ex2((2.0f * L2E) * c));
    float tc = fmaf(-2.0f, rc, 1.0f);        // tanh(c)
    h = ro * tc;
}

__global__ __launch_bounds__(64) void lstm_chain_kernel(
    const float* __restrict__ x, const float* __restrict__ t,
    const float* __restrict__ h0, const float* __restrict__ c0,
    const float* __restrict__ w_ih, const float* __restrict__ w_hh,
    const float* __restrict__ b_ih, const float* __restrict__ b_hh,
    float* __restrict__ out)
{
    const int b = blockIdx.x * 64 + threadIdx.x;

    Consts K;
    {
        float bi = b_ih[0] + b_hh[0], bf = b_ih[1] + b_hh[1];
        float bg = b_ih[2] + b_hh[2], bo = b_ih[3] + b_hh[3];
        K.Ai = -L2E * w_ih[0]; K.Bi = -L2E * w_hh[0]; K.Ci = -L2E * bi;
        K.Af = -L2E * w_ih[1]; K.Bf = -L2E * w_hh[1]; K.Cf = -L2E * bf;
        K.Ag =  2.0f * L2E * w_ih[2]; K.Bg = 2.0f * L2E * w_hh[2]; K.Cg = 2.0f * L2E * bg;
        K.Ao = -L2E * w_ih[3]; K.Bo = -L2E * w_hh[3]; K.Co = -L2E * bo;
    }

    float h = h0[b];
    float c = c0[b];

    // ---- open loop: 1024 steps over x[b, :] ----
    const float4* xr = (const float4*)(x + (size_t)b * T_IN);
    float4 buf0 = xr[0];
    float4 buf1 = xr[1];
    #pragma unroll 1
    for (int q = 0; q < T_IN / 4; ++q) {
        int pf = q + 2; if (pf > T_IN / 4 - 1) pf = T_IN / 4 - 1;
        float4 nxt = xr[pf];
        lstm_step(buf0.x, h, c, K);
        lstm_step(buf0.y, h, c, K);
        lstm_step(buf0.z, h, c, K);
        lstm_step(buf0.w, h, c, K);
        buf0 = buf1;
        buf1 = nxt;
    }
    // after the loop buf0 == xr[255] (the last group), so buf0.w == x[b,1023]
    float xin = buf0.w;

    // ---- closed loop: 512 autoregressive steps, preds + loss ----
    const float4* tr = (const float4*)(t + (size_t)b * STEPS);
    float* po = out + 1 + (size_t)b * STEPS;   // 4B-aligned only -> scalar stores
    float lacc = 0.0f;
    float4 t0 = tr[0];
    float4 t1 = tr[1];
    #pragma unroll 1
    for (int q = 0; q < STEPS / 4; ++q) {
        int pf = q + 2; if (pf > STEPS / 4 - 1) pf = STEPS / 4 - 1;
        float4 tn = tr[pf];
        float p0, p1, p2, p3;
        lstm_step(xin, h, c, K); p0 = h; xin = h;
        lstm_step(xin, h, c, K); p1 = h; xin = h;
        lstm_step(xin, h, c, K); p2 = h; xin = h;
        lstm_step(xin, h, c, K); p3 = h; xin = h;
        float d0 = p0 - t0.x, d1 = p1 - t0.y, d2 = p2 - t0.z, d3 = p3 - t0.w;
        lacc = fmaf(d0, d0, lacc);
        lacc = fmaf(d1, d1, lacc);
        lacc = fmaf(d2, d2, lacc);
        lacc = fmaf(d3, d3, lacc);
        po[q * 4 + 0] = p0;
        po[q * 4 + 1] = p1;
        po[q * 4 + 2] = p2;
        po[q * 4 + 3] = p3;
        t0 = t1;
        t1 = tn;
    }

    // ---- loss reduction: wave64 shuffle + one atomic per block ----
    #pragma unroll
    for (int off = 32; off > 0; off >>= 1)
        lacc += __shfl_down(lacc, off, 64);
    if (threadIdx.x == 0)
        atomicAdd(out, lacc * (1.0f / (float)B_TOT));
}

extern "C" void kernel_launch(void* const* d_in, const int* in_sizes, int n_in,
                              void* d_out, int out_size, void* d_ws, size_t ws_size,
                              hipStream_t stream) {
    const float* x    = (const float*)d_in[0];
    const float* t    = (const float*)d_in[1];
    const float* h0   = (const float*)d_in[2];
    const float* c0   = (const float*)d_in[3];
    const float* w_ih = (const float*)d_in[4];
    const float* w_hh = (const float*)d_in[5];
    const float* b_ih = (const float*)d_in[6];
    const float* b_hh = (const float*)d_in[7];
    float* out = (float*)d_out;

    // loss accumulator must start at 0 (d_out is poisoned before every launch)
    hipMemsetAsync(out, 0, sizeof(float), stream);

    lstm_chain_kernel<<<B_TOT / 64, 64, 0, stream>>>(
        x, t, h0, c0, w_ih, w_hh, b_ih, b_hh, out);
}

// Round 2
// 355.403 us; speedup vs baseline: 1.0282x; 1.0282x over previous
//
#include <hip/hip_runtime.h>

// Hidden-size-1 LSTM, B=32768 chains, 1024 open + 512 closed steps.
// One thread per chain, 64-thread blocks (1 wave) each owning 64 chains.
// All global traffic coalesced via LDS staging (rows padded to 65 floats:
// bank = (b+s) mod 32 -> 2 lanes/bank = conflict-free on wave64).
// sigmoid(z) = 1/(1+exp2(-L2E*z)); tanh(z) = 1 - 2/(1+exp2(2*L2E*z)).

#define L2E 1.44269504088896340736f
#define B_TOT 32768
#define T_IN 1024
#define STEPS 512
#define CH 64
#define PAD 65

__device__ __forceinline__ float ex2(float x){ return __builtin_amdgcn_exp2f(x); }
__device__ __forceinline__ float rcp(float x){ return __builtin_amdgcn_rcpf(x); }

struct K8 { float Ai,Bi,Ci, Af,Bf,Cf, Ag,Bg,Cg, Ao,Bo,Co; };
struct K4 { float Wi,Ci, Wf,Cf, Wg,Cg, Wo,Co; };

__device__ __forceinline__ void step_open(float xv, float& h, float& c, const K8& K){
    float zi = fmaf(h, K.Bi, fmaf(xv, K.Ai, K.Ci));
    float zf = fmaf(h, K.Bf, fmaf(xv, K.Af, K.Cf));
    float zg = fmaf(h, K.Bg, fmaf(xv, K.Ag, K.Cg));
    float zo = fmaf(h, K.Bo, fmaf(xv, K.Ao, K.Co));
    float ri = rcp(1.0f + ex2(zi));
    float rf = rcp(1.0f + ex2(zf));
    float rg = rcp(1.0f + ex2(zg));
    float ro = rcp(1.0f + ex2(zo));
    float g  = fmaf(-2.0f, rg, 1.0f);
    c = fmaf(rf, c, ri * g);
    float rc = rcp(1.0f + ex2((2.0f * L2E) * c));
    h = ro * fmaf(-2.0f, rc, 1.0f);
}

__device__ __forceinline__ void step_closed(float& h, float& c, const K4& K){
    float zi = fmaf(h, K.Wi, K.Ci);
    float zf = fmaf(h, K.Wf, K.Cf);
    float zg = fmaf(h, K.Wg, K.Cg);
    float zo = fmaf(h, K.Wo, K.Co);
    float ri = rcp(1.0f + ex2(zi));
    float rf = rcp(1.0f + ex2(zf));
    float rg = rcp(1.0f + ex2(zg));
    float ro = rcp(1.0f + ex2(zo));
    float g  = fmaf(-2.0f, rg, 1.0f);
    c = fmaf(rf, c, ri * g);
    float rc = rcp(1.0f + ex2((2.0f * L2E) * c));
    h = ro * fmaf(-2.0f, rc, 1.0f);
}

// Coalesced load of a 64-row x CH-col chunk into 16 float4/lane.
// inst j covers rows j*4 .. j*4+3; lanes 0..15 cover one row's 64 floats.
__device__ __forceinline__ void stage_issue(const float* __restrict__ base,
                                            int row_stride, int col0, int lane,
                                            float4* v){
    const int r_lo = lane >> 4;        // 0..3
    const int c4   = lane & 15;        // 0..15
    #pragma unroll
    for (int j = 0; j < 16; ++j){
        int r = j * 4 + r_lo;
        v[j] = *(const float4*)(base + (size_t)r * row_stride + col0 + c4 * 4);
    }
}
// Write the staged chunk into LDS with PAD row stride (scalar b32 writes:
// PAD=65 makes rows only 4B-aligned).
__device__ __forceinline__ void stage_write(float* __restrict__ lds, int lane,
                                            const float4* v){
    const int r_lo = lane >> 4;
    const int c4   = lane & 15;
    #pragma unroll
    for (int j = 0; j < 16; ++j){
        int r = j * 4 + r_lo;
        float* p = lds + r * PAD + c4 * 4;
        p[0] = v[j].x; p[1] = v[j].y; p[2] = v[j].z; p[3] = v[j].w;
    }
}

__global__ __launch_bounds__(64) void lstm_chain_kernel(
    const float* __restrict__ x, const float* __restrict__ t,
    const float* __restrict__ h0, const float* __restrict__ c0,
    const float* __restrict__ w_ih, const float* __restrict__ w_hh,
    const float* __restrict__ b_ih, const float* __restrict__ b_hh,
    float* __restrict__ out)
{
    __shared__ float sb[2][64 * PAD];   // x/t staging, double-buffered
    __shared__ float pb[64 * PAD];      // pred staging

    const int lane = threadIdx.x;
    const int b0 = blockIdx.x * 64;
    const int b = b0 + lane;

    K8 K; K4 K2;
    {
        float bi = b_ih[0] + b_hh[0], bf = b_ih[1] + b_hh[1];
        float bg = b_ih[2] + b_hh[2], bo = b_ih[3] + b_hh[3];
        K.Ai = -L2E * w_ih[0]; K.Bi = -L2E * w_hh[0]; K.Ci = -L2E * bi;
        K.Af = -L2E * w_ih[1]; K.Bf = -L2E * w_hh[1]; K.Cf = -L2E * bf;
        K.Ag =  2.0f * L2E * w_ih[2]; K.Bg = 2.0f * L2E * w_hh[2]; K.Cg = 2.0f * L2E * bg;
        K.Ao = -L2E * w_ih[3]; K.Bo = -L2E * w_hh[3]; K.Co = -L2E * bo;
        K2.Wi = K.Ai + K.Bi; K2.Ci = K.Ci;
        K2.Wf = K.Af + K.Bf; K2.Cf = K.Cf;
        K2.Wg = K.Ag + K.Bg; K2.Cg = K.Cg;
        K2.Wo = K.Ao + K.Bo; K2.Co = K.Co;
    }

    float h = h0[b];
    float c = c0[b];

    const float* xbase = x + (size_t)b0 * T_IN;
    const float* tbase = t + (size_t)b0 * STEPS;

    // ---- open loop: 16 chunks of 64 steps ----
    {
        float4 stg[16];
        stage_issue(xbase, T_IN, 0, lane, stg);
        stage_write(sb[0], lane, stg);
    }
    #pragma unroll 1
    for (int k = 0; k < T_IN / CH; ++k){
        float4 stg2[16];
        if (k < T_IN / CH - 1) stage_issue(xbase, T_IN, (k + 1) * CH, lane, stg2);
        const float* xrow = &sb[k & 1][lane * PAD];
        #pragma unroll 4
        for (int s = 0; s < CH; ++s){
            step_open(xrow[s], h, c, K);
        }
        if (k < T_IN / CH - 1) stage_write(sb[(k + 1) & 1], lane, stg2);
    }
    float xin = sb[(T_IN / CH - 1) & 1][lane * PAD + (CH - 1)];  // x[b, 1023]

    // ---- closed loop: 8 chunks of 64 steps ----
    {
        float4 stg[16];
        stage_issue(tbase, STEPS, 0, lane, stg);
        stage_write(sb[0], lane, stg);
    }
    float lacc = 0.0f;
    #pragma unroll 1
    for (int k = 0; k < STEPS / CH; ++k){
        float4 stg2[16];
        if (k < STEPS / CH - 1) stage_issue(tbase, STEPS, (k + 1) * CH, lane, stg2);
        const float* trow = &sb[k & 1][lane * PAD];
        float* prow = &pb[lane * PAD];
        #pragma unroll 4
        for (int s = 0; s < CH; ++s){
            if (k == 0 && s == 0) step_open(xin, h, c, K);
            else                  step_closed(h, c, K2);
            float d = h - trow[s];
            lacc = fmaf(d, d, lacc);
            prow[s] = h;
        }
        // flush preds: row-wise coalesced stores (64 consecutive dwords/inst)
        float* obase = out + 1 + (size_t)b0 * STEPS + k * CH + lane;
        #pragma unroll 4
        for (int r = 0; r < 64; ++r){
            obase[(size_t)r * STEPS] = pb[r * PAD + lane];
        }
        if (k < STEPS / CH - 1) stage_write(sb[(k + 1) & 1], lane, stg2);
    }

    // ---- loss reduction: wave64 shuffle + one atomic per block ----
    #pragma unroll
    for (int off = 32; off > 0; off >>= 1)
        lacc += __shfl_down(lacc, off, 64);
    if (lane == 0)
        atomicAdd(out, lacc * (1.0f / (float)B_TOT));
}

extern "C" void kernel_launch(void* const* d_in, const int* in_sizes, int n_in,
                              void* d_out, int out_size, void* d_ws, size_t ws_size,
                              hipStream_t stream) {
    const float* x    = (const float*)d_in[0];
    const float* t    = (const float*)d_in[1];
    const float* h0   = (const float*)d_in[2];
    const float* c0   = (const float*)d_in[3];
    const float* w_ih = (const float*)d_in[4];
    const float* w_hh = (const float*)d_in[5];
    const float* b_ih = (const float*)d_in[6];
    const float* b_hh = (const float*)d_in[7];
    float* out = (float*)d_out;

    hipMemsetAsync(out, 0, sizeof(float), stream);

    lstm_chain_kernel<<<B_TOT / 64, 64, 0, stream>>>(
        x, t, h0, c0, w_ih, w_hh, b_ih, b_hh, out);
}

// Round 3
// 331.136 us; speedup vs baseline: 1.1035x; 1.0733x over previous
//
#include <hip/hip_runtime.h>

// Hidden-size-1 LSTM, B=32768 chains, 1024 open + 512 closed steps.
// TWO LANES PER CHAIN: even lane computes gates (i,g), odd lane (f,o);
// activation results exchanged via DPP quad_perm(1,0,3,2) (full-rate VALU).
// 1024 waves (32 chains each) -> one wave on every SIMD of all 256 CUs.
// c kept pre-scaled: C = 2*log2(e)*c, so tanh(c) = 1 - 2*rcp(1+exp2(C)).
// sigma(z) = rcp(1+exp2(-L2E*z)); tanh(z) = 1 - 2*rcp(1+exp2(2*L2E*z)).

#define L2E 1.44269504088896340736f
#define B_TOT 32768
#define T_IN 1024
#define STEPS 512
#define CPB 32          // chains per block (one wave)
#define CH 64           // chunk length in steps
#define PAD 65          // LDS row stride: bank = (chain + s) % 32, pair-broadcast reads

__device__ __forceinline__ float ex2(float x){ return __builtin_amdgcn_exp2f(x); }
__device__ __forceinline__ float rcp(float x){ return __builtin_amdgcn_rcpf(x); }
__device__ __forceinline__ float dpp_swap1(float v){
    // quad_perm [1,0,3,2]: swap adjacent lanes within each quad
    return __int_as_float(__builtin_amdgcn_mov_dpp(__float_as_int(v), 0xB1, 0xF, 0xF, true));
}

struct LaneK { float A1,B1,C1, A2,B2,C2, W1,W2; };

// z1/z2 are this lane's two gate pre-activations (already scale-folded).
// even lane: z1 = i-gate (-L2E), z2 = g-gate (+2*L2E)
// odd  lane: z1 = f-gate (-L2E), z2 = o-gate (-L2E)
__device__ __forceinline__ void finish_step(float z1, float z2, bool odd,
                                            float& h, float& C){
    float e1 = ex2(z1);
    float e2 = ex2(z2);
    float r1 = rcp(1.0f + e1);
    float r2 = rcp(1.0f + e2);
    float s1 = dpp_swap1(r1);
    float s2 = dpp_swap1(r2);
    float ri = odd ? s1 : r1;     // sigma(zi)
    float rf = odd ? r1 : s1;     // sigma(zf)
    float rg = odd ? s2 : r2;     // 1/(1+e^{2 zg})
    float ro = odd ? r2 : s2;     // sigma(zo)
    float g2  = fmaf(rg, -4.0f * L2E, 2.0f * L2E);   // 2*L2E*tanh(zg)
    float rfC = rf * C;
    C = fmaf(ri, g2, rfC);                            // C = 2*L2E*c_new
    float rc = rcp(1.0f + ex2(C));
    float u  = rc + rc;
    h = fmaf(-u, ro, ro);                             // h = ro*(1-2rc)
}

// stage a 32-row x 64-col chunk: 8 float4 per lane, coalesced
__device__ __forceinline__ void stage_issue32(const float* __restrict__ base,
                                              int row_stride, int col0, int lane,
                                              float4* v){
    const int r_lo = lane >> 4, c4 = lane & 15;
    #pragma unroll
    for (int j = 0; j < 8; ++j)
        v[j] = *(const float4*)(base + (size_t)(j*4 + r_lo) * row_stride + col0 + c4*4);
}
__device__ __forceinline__ void stage_write32(float* __restrict__ lds, int lane,
                                              const float4* v){
    const int r_lo = lane >> 4, c4 = lane & 15;
    #pragma unroll
    for (int j = 0; j < 8; ++j){
        float* p = lds + (j*4 + r_lo) * PAD + c4*4;
        p[0]=v[j].x; p[1]=v[j].y; p[2]=v[j].z; p[3]=v[j].w;
    }
}

__global__ __launch_bounds__(64) void lstm_chain_kernel(
    const float* __restrict__ x, const float* __restrict__ t,
    const float* __restrict__ h0, const float* __restrict__ c0,
    const float* __restrict__ w_ih, const float* __restrict__ w_hh,
    const float* __restrict__ b_ih, const float* __restrict__ b_hh,
    float* __restrict__ out)
{
    __shared__ float sb[2][CPB * PAD];   // x/t staging, double-buffered
    __shared__ float pb[CPB * PAD];      // pred staging

    const int lane = threadIdx.x;
    const bool odd = lane & 1;
    const int ch   = lane >> 1;          // chain within block
    const int b0   = blockIdx.x * CPB;

    LaneK K;
    {
        float bi = b_ih[0] + b_hh[0], bf = b_ih[1] + b_hh[1];
        float bg = b_ih[2] + b_hh[2], bo = b_ih[3] + b_hh[3];
        float Ai = -L2E*w_ih[0], Bi = -L2E*w_hh[0], Ci = -L2E*bi;
        float Af = -L2E*w_ih[1], Bf = -L2E*w_hh[1], Cf = -L2E*bf;
        float Ag = 2.0f*L2E*w_ih[2], Bg = 2.0f*L2E*w_hh[2], Cg = 2.0f*L2E*bg;
        float Ao = -L2E*w_ih[3], Bo = -L2E*w_hh[3], Co = -L2E*bo;
        K.A1 = odd ? Af : Ai;  K.B1 = odd ? Bf : Bi;  K.C1 = odd ? Cf : Ci;
        K.A2 = odd ? Ao : Ag;  K.B2 = odd ? Bo : Bg;  K.C2 = odd ? Co : Cg;
        K.W1 = K.A1 + K.B1;    K.W2 = K.A2 + K.B2;    // closed loop: x_in = h
    }

    float h = h0[b0 + ch];
    float C = (2.0f * L2E) * c0[b0 + ch];

    const float* xbase = x + (size_t)b0 * T_IN;
    const float* tbase = t + (size_t)b0 * STEPS;

    // ---- open loop: 16 chunks of 64 steps ----
    { float4 stg[8]; stage_issue32(xbase, T_IN, 0, lane, stg); stage_write32(sb[0], lane, stg); }
    #pragma unroll 1
    for (int k = 0; k < T_IN / CH; ++k){
        float4 stg[8];
        if (k < T_IN/CH - 1) stage_issue32(xbase, T_IN, (k+1)*CH, lane, stg);
        const float* xrow = &sb[k & 1][ch * PAD];
        #pragma unroll 4
        for (int s = 0; s < CH; ++s){
            float xv = xrow[s];
            float z1 = fmaf(xv, K.A1, fmaf(h, K.B1, K.C1));
            float z2 = fmaf(xv, K.A2, fmaf(h, K.B2, K.C2));
            finish_step(z1, z2, odd, h, C);
        }
        if (k < T_IN/CH - 1) stage_write32(sb[(k+1) & 1], lane, stg);
    }
    float xin = sb[(T_IN/CH - 1) & 1][ch * PAD + (CH - 1)];  // x[b, 1023]

    // ---- closed loop: 8 chunks of 64 steps ----
    { float4 stg[8]; stage_issue32(tbase, STEPS, 0, lane, stg); stage_write32(sb[0], lane, stg); }
    float lacc = 0.0f;

    auto cstep = [&](int s, const float* trow, float* prow){
        float z1 = fmaf(h, K.W1, K.C1);
        float z2 = fmaf(h, K.W2, K.C2);
        finish_step(z1, z2, odd, h, C);
        float d = h - trow[s];
        lacc = fmaf(d, d, lacc);
        prow[s] = h;
    };

    #pragma unroll 1
    for (int k = 0; k < STEPS / CH; ++k){
        float4 stg[8];
        if (k < STEPS/CH - 1) stage_issue32(tbase, STEPS, (k+1)*CH, lane, stg);
        const float* trow = &sb[k & 1][ch * PAD];
        float* prow = &pb[ch * PAD];
        if (k == 0){
            // first closed step feeds x[b,1023], not h
            float z1 = fmaf(xin, K.A1, fmaf(h, K.B1, K.C1));
            float z2 = fmaf(xin, K.A2, fmaf(h, K.B2, K.C2));
            finish_step(z1, z2, odd, h, C);
            float d = h - trow[0];
            lacc = fmaf(d, d, lacc);
            prow[0] = h;
            #pragma unroll 4
            for (int s = 1; s < CH; ++s) cstep(s, trow, prow);
        } else {
            #pragma unroll 4
            for (int s = 0; s < CH; ++s) cstep(s, trow, prow);
        }
        // flush preds: 32 rows, 64 consecutive floats per store instruction
        float* obase = out + 1 + (size_t)b0 * STEPS + k * CH;
        #pragma unroll 4
        for (int r = 0; r < CPB; ++r)
            obase[(size_t)r * STEPS + lane] = pb[r * PAD + lane];
        if (k < STEPS/CH - 1) stage_write32(sb[(k+1) & 1], lane, stg);
    }

    // ---- loss: both lanes of a pair hold identical lacc -> scale by 0.5 ----
    #pragma unroll
    for (int off = 32; off > 0; off >>= 1)
        lacc += __shfl_down(lacc, off, 64);
    if (lane == 0)
        atomicAdd(out, lacc * (0.5f / (float)B_TOT));
}

extern "C" void kernel_launch(void* const* d_in, const int* in_sizes, int n_in,
                              void* d_out, int out_size, void* d_ws, size_t ws_size,
                              hipStream_t stream) {
    const float* x    = (const float*)d_in[0];
    const float* t    = (const float*)d_in[1];
    const float* h0   = (const float*)d_in[2];
    const float* c0   = (const float*)d_in[3];
    const float* w_ih = (const float*)d_in[4];
    const float* w_hh = (const float*)d_in[5];
    const float* b_ih = (const float*)d_in[6];
    const float* b_hh = (const float*)d_in[7];
    float* out = (float*)d_out;

    hipMemsetAsync(out, 0, sizeof(float), stream);

    lstm_chain_kernel<<<B_TOT / CPB, 64, 0, stream>>>(
        x, t, h0, c0, w_ih, w_hh, b_ih, b_hh, out);
}